// Round 16
// baseline (523.766 us; speedup 1.0000x reference)
//
#include <hip/hip_runtime.h>
#include <hip/hip_bf16.h>
#include <cstddef>
#include <cstdint>

#define FLT_MAX_C 3.402823466e+38f

typedef __attribute__((ext_vector_type(8))) __bf16 bf16x8;
typedef __attribute__((ext_vector_type(16))) float f32x16;

// Truncation-based fp32 -> bf16(hi) + bf16(lo) split (bit-exact, r4/9/12).
__device__ __forceinline__ void split8(const float* v, uint4& hi, uint4& lo) {
    uint32_t hu[8], lu[8];
#pragma unroll
    for (int e = 0; e < 8; ++e) {
        union { float f; uint32_t u; } a, t, d;
        a.f = v[e];
        t.u = a.u & 0xffff0000u;
        d.f = a.f - t.f;
        hu[e] = t.u;
        lu[e] = d.u;
    }
    hi.x = __builtin_amdgcn_perm(hu[1], hu[0], 0x07060302u);
    hi.y = __builtin_amdgcn_perm(hu[3], hu[2], 0x07060302u);
    hi.z = __builtin_amdgcn_perm(hu[5], hu[4], 0x07060302u);
    hi.w = __builtin_amdgcn_perm(hu[7], hu[6], 0x07060302u);
    lo.x = __builtin_amdgcn_perm(lu[1], lu[0], 0x07060302u);
    lo.y = __builtin_amdgcn_perm(lu[3], lu[2], 0x07060302u);
    lo.z = __builtin_amdgcn_perm(lu[5], lu[4], 0x07060302u);
    lo.w = __builtin_amdgcn_perm(lu[7], lu[6], 0x07060302u);
}

// LDS-only barrier (r12, proven): drain ds ops so LDS writes are visible,
// leave GLOBAL loads (vmcnt) in flight across the barrier.
__device__ __forceinline__ void lds_barrier() {
    asm volatile("s_waitcnt lgkmcnt(0)" ::: "memory");
    __builtin_amdgcn_s_barrier();
}

// ---------------------------------------------------------------------------
// 64x64 split-bf16 3-pass MFMA GEMM, BK=64 (NEW this round): per-output
// accumulation BIT-IDENTICAL to r12's BK=32 — each 64-k step issues the
// exact MFMA sequence of two consecutive r12 steps:
//   chunk0: accA(k0-15: hh,hl,lh) interleaved accB(k16-31),
//   chunk1: accA(k32-47) interleaved accB(k48-63).
// Tail zero-padding lands at the same k-positions in the same order as r12
// (6000 = 93*64+48; masked loads give the same zero-adds).
// Change vs r12 is SYNC FREQUENCY only: 94 barriers instead of 188, LDS
// 64 KiB (2 blocks/CU, 8 waves — the experiment's risk side). Single
// staging regset: one-step lookahead (~2600 cyc) >> HBM latency.
// Requires Ma % 64 == 0.
// ---------------------------------------------------------------------------
template<bool ADD_BIAS>
__global__ __launch_bounds__(256) void gemm_mfma_split64(
    const float* __restrict__ A, const float* __restrict__ Bm,
    const float* __restrict__ bias, float* __restrict__ C,
    int Ma, int Na, int K)
{
    __shared__ alignas(16) unsigned short As_hi[2][4096];
    __shared__ alignas(16) unsigned short As_lo[2][4096];
    __shared__ alignas(16) unsigned short Bs_hi[2][4096];
    __shared__ alignas(16) unsigned short Bs_lo[2][4096];

    const int nby = Ma >> 6;
    const int nwg = gridDim.x;
    const int orig = blockIdx.x;
    const int qq = nwg >> 3, rr = nwg & 7;
    const int xcd = orig & 7, lin = orig >> 3;
    const int wg = ((xcd < rr) ? xcd * (qq + 1) : rr * (qq + 1) + (xcd - rr) * qq) + lin;
    const int by = wg % nby;
    const int bx = wg / nby;

    const int m0 = by * 64;
    const int n0 = bx * 64;

    const int tid  = threadIdx.x;
    const int lane = tid & 63;
    const int wid  = tid >> 6;
    const int wm   = wid >> 1;
    const int wn   = wid & 1;

    // staging: thread -> (row ra, k-slot sa in 0..3); stages slots sa, sa+4
    const int ra = tid & 63, sa = tid >> 6;

    const float* aB = A + (size_t)(m0 + ra) * K + sa * 8;
    const int gnb = n0 + ra;
    const float* bB = (gnb < Na) ? (Bm + (size_t)gnb * K + sa * 8) : nullptr;

    const int wOff0 = (sa * 64 + ra) * 8;          // slot sa
    const int wOff1 = ((sa + 4) * 64 + ra) * 8;    // slot sa+4

    // fragment offsets per 32-k chunk c: slots c*4+kh and c*4+2+kh
    const int lr = lane & 31, kh = lane >> 5;
    const int arow = wm * 32 + lr;
    const int brow = wn * 32 + lr;
    const int a00 = ((0 * 4 + kh)     * 64 + arow) * 8;
    const int a01 = ((0 * 4 + 2 + kh) * 64 + arow) * 8;
    const int a10 = ((1 * 4 + kh)     * 64 + arow) * 8;
    const int a11 = ((1 * 4 + 2 + kh) * 64 + arow) * 8;
    const int b00 = ((0 * 4 + kh)     * 64 + brow) * 8;
    const int b01 = ((0 * 4 + 2 + kh) * 64 + brow) * 8;
    const int b10 = ((1 * 4 + kh)     * 64 + brow) * 8;
    const int b11 = ((1 * 4 + 2 + kh) * 64 + brow) * 8;

    float ar_[16], br_[16];
#pragma unroll
    for (int e = 0; e < 16; ++e) br_[e] = 0.0f;

    auto load_grp = [&](const float* base, float* dst, int koff, int kend) {
        if (koff + 8 <= kend) {
            float4 v0 = *(const float4*)(base);
            float4 v1 = *(const float4*)(base + 4);
            dst[0]=v0.x; dst[1]=v0.y; dst[2]=v0.z; dst[3]=v0.w;
            dst[4]=v1.x; dst[5]=v1.y; dst[6]=v1.z; dst[7]=v1.w;
        } else {
#pragma unroll
            for (int e = 0; e < 8; ++e)
                dst[e] = (koff + e < kend) ? base[e] : 0.0f;
        }
    };

    auto load_regs = [&](int s) {
        const int k0 = s << 6;
        load_grp(aB + k0,      ar_,     k0 + sa * 8,      K);
        load_grp(aB + k0 + 32, ar_ + 8, k0 + 32 + sa * 8, K);
        if (bB) {
            load_grp(bB + k0,      br_,     k0 + sa * 8,      K);
            load_grp(bB + k0 + 32, br_ + 8, k0 + 32 + sa * 8, K);
        }
    };

    auto write_tile = [&](int buf) {
        uint4 hi, lo;
        split8(ar_, hi, lo);
        *(uint4*)&As_hi[buf][wOff0] = hi;
        *(uint4*)&As_lo[buf][wOff0] = lo;
        split8(ar_ + 8, hi, lo);
        *(uint4*)&As_hi[buf][wOff1] = hi;
        *(uint4*)&As_lo[buf][wOff1] = lo;
        split8(br_, hi, lo);
        *(uint4*)&Bs_hi[buf][wOff0] = hi;
        *(uint4*)&Bs_lo[buf][wOff0] = lo;
        split8(br_ + 8, hi, lo);
        *(uint4*)&Bs_hi[buf][wOff1] = hi;
        *(uint4*)&Bs_lo[buf][wOff1] = lo;
    };

    f32x16 accA, accB;
#pragma unroll
    for (int i = 0; i < 16; ++i) { accA[i] = 0.0f; accB[i] = 0.0f; }

    const int nsteps = (K + 63) >> 6;

    // prologue: tile 0 staged to buf0; regs <- tile 1 (in flight)
    load_regs(0);
    write_tile(0);
    if (nsteps > 1) load_regs(1);
    __syncthreads();

    for (int s = 0; s < nsteps; ++s) {
        const int cur = s & 1;

        // 1) all fragment reads issue first (buf[cur], disjoint from staging)
        bf16x8 c0a0h = *(const bf16x8*)&As_hi[cur][a00];
        bf16x8 c0a0l = *(const bf16x8*)&As_lo[cur][a00];
        bf16x8 c0a1h = *(const bf16x8*)&As_hi[cur][a01];
        bf16x8 c0a1l = *(const bf16x8*)&As_lo[cur][a01];
        bf16x8 c0b0h = *(const bf16x8*)&Bs_hi[cur][b00];
        bf16x8 c0b0l = *(const bf16x8*)&Bs_lo[cur][b00];
        bf16x8 c0b1h = *(const bf16x8*)&Bs_hi[cur][b01];
        bf16x8 c0b1l = *(const bf16x8*)&Bs_lo[cur][b01];
        bf16x8 c1a0h = *(const bf16x8*)&As_hi[cur][a10];
        bf16x8 c1a0l = *(const bf16x8*)&As_lo[cur][a10];
        bf16x8 c1a1h = *(const bf16x8*)&As_hi[cur][a11];
        bf16x8 c1a1l = *(const bf16x8*)&As_lo[cur][a11];
        bf16x8 c1b0h = *(const bf16x8*)&Bs_hi[cur][b10];
        bf16x8 c1b0l = *(const bf16x8*)&Bs_lo[cur][b10];
        bf16x8 c1b1h = *(const bf16x8*)&Bs_hi[cur][b11];
        bf16x8 c1b1l = *(const bf16x8*)&Bs_lo[cur][b11];

        // 2) write_tile BEFORE load_regs (regs hold tile s+1 — r8 lesson)
        if (s + 1 < nsteps) write_tile(cur ^ 1);
        if (s + 2 < nsteps) load_regs(s + 2);

        // 3) 12 MFMAs = exactly two consecutive r12 steps (bit-identical)
        __builtin_amdgcn_s_setprio(1);
        accA = __builtin_amdgcn_mfma_f32_32x32x16_bf16(c0a0h, c0b0h, accA, 0,0,0);
        accB = __builtin_amdgcn_mfma_f32_32x32x16_bf16(c0a1h, c0b1h, accB, 0,0,0);
        accA = __builtin_amdgcn_mfma_f32_32x32x16_bf16(c0a0h, c0b0l, accA, 0,0,0);
        accB = __builtin_amdgcn_mfma_f32_32x32x16_bf16(c0a1h, c0b1l, accB, 0,0,0);
        accA = __builtin_amdgcn_mfma_f32_32x32x16_bf16(c0a0l, c0b0h, accA, 0,0,0);
        accB = __builtin_amdgcn_mfma_f32_32x32x16_bf16(c0a1l, c0b1h, accB, 0,0,0);
        accA = __builtin_amdgcn_mfma_f32_32x32x16_bf16(c1a0h, c1b0h, accA, 0,0,0);
        accB = __builtin_amdgcn_mfma_f32_32x32x16_bf16(c1a1h, c1b1h, accB, 0,0,0);
        accA = __builtin_amdgcn_mfma_f32_32x32x16_bf16(c1a0h, c1b0l, accA, 0,0,0);
        accB = __builtin_amdgcn_mfma_f32_32x32x16_bf16(c1a1h, c1b1l, accB, 0,0,0);
        accA = __builtin_amdgcn_mfma_f32_32x32x16_bf16(c1a0l, c1b0h, accA, 0,0,0);
        accB = __builtin_amdgcn_mfma_f32_32x32x16_bf16(c1a1l, c1b1h, accB, 0,0,0);
        __builtin_amdgcn_s_setprio(0);

        // 4) LDS-only barrier (94 per block instead of 188)
        lds_barrier();
    }

    f32x16 acc;
#pragma unroll
    for (int i = 0; i < 16; ++i) acc[i] = accA[i] + accB[i];

    // C/D layout: col=lane&31, row=(reg&3)+8*(reg>>2)+4*(lane>>5)
    const int col = lane & 31;
    const int rbase = 4 * kh;
#pragma unroll
    for (int r = 0; r < 16; ++r) {
        const int row = (r & 3) + 8 * (r >> 2) + rbase;
        const int gm = m0 + wm * 32 + row;
        const int gn = n0 + wn * 32 + col;
        if (gn < Na) {
            float v = acc[r];
            if (ADD_BIAS) v += bias[gn];
            C[(size_t)gm * Na + gn] = v;
        }
    }
}

// ---------------------------------------------------------------------------
// 32x64 / 2-wave variant — EXACT r10/r15 kernel (passed; bit-identical per
// output). Used for the small GEMMs (z_a, out). Requires Ma % 32 == 0.
// ---------------------------------------------------------------------------
template<bool ADD_BIAS>
__global__ __launch_bounds__(128) void gemm_mfma_split32(
    const float* __restrict__ A, const float* __restrict__ Bm,
    const float* __restrict__ bias, float* __restrict__ C,
    int Ma, int Na, int K)
{
    __shared__ alignas(16) unsigned short As_hi[2][1024];
    __shared__ alignas(16) unsigned short As_lo[2][1024];
    __shared__ alignas(16) unsigned short Bs_hi[2][2048];
    __shared__ alignas(16) unsigned short Bs_lo[2][2048];

    const int nby = Ma >> 5;
    const int nwg = gridDim.x;
    const int orig = blockIdx.x;
    const int qq = nwg >> 3, rr = nwg & 7;
    const int xcd = orig & 7, lin = orig >> 3;
    const int wg = ((xcd < rr) ? xcd * (qq + 1) : rr * (qq + 1) + (xcd - rr) * qq) + lin;
    const int by = wg % nby;
    const int bx = wg / nby;

    const int m0 = by * 32;
    const int n0 = bx * 64;

    const int tid  = threadIdx.x;
    const int lane = tid & 63;
    const int wid  = tid >> 6;

    const int ra = tid & 31, sa = tid >> 5;
    const int rb = tid & 63, sb2 = tid >> 6;

    const float* aB = A + (size_t)(m0 + ra) * K + sa * 8;
    const int gnb = n0 + rb;
    const float* bB = (gnb < Na) ? (Bm + (size_t)gnb * K + sb2 * 8) : nullptr;

    const int wOffA  = (sa * 32 + ra) * 8;
    const int wOffB0 = (sb2 * 64 + rb) * 8;
    const int wOffB1 = ((sb2 + 2) * 64 + rb) * 8;

    const int lr = lane & 31, kh = lane >> 5;
    const int brow = wid * 32 + lr;
    const int aOff0 = ((kh)     * 32 + lr) * 8;
    const int aOff1 = ((2 + kh) * 32 + lr) * 8;
    const int bOff0 = ((kh)     * 64 + brow) * 8;
    const int bOff1 = ((2 + kh) * 64 + brow) * 8;

    float ar_[8];
    float br_[16];
#pragma unroll
    for (int e = 0; e < 16; ++e) br_[e] = 0.0f;

    auto load_regs = [&](int s) {
        const int k0 = s << 5;
        const int ka = k0 + sa * 8;
        if (ka + 8 <= K) {
            float4 v0 = *(const float4*)(aB + k0);
            float4 v1 = *(const float4*)(aB + k0 + 4);
            ar_[0]=v0.x; ar_[1]=v0.y; ar_[2]=v0.z; ar_[3]=v0.w;
            ar_[4]=v1.x; ar_[5]=v1.y; ar_[6]=v1.z; ar_[7]=v1.w;
        } else {
#pragma unroll
            for (int e = 0; e < 8; ++e)
                ar_[e] = (ka + e < K) ? aB[k0 + e] : 0.0f;
        }
        if (bB) {
            const int kb0 = k0 + sb2 * 8;
            if (kb0 + 8 <= K) {
                float4 w0 = *(const float4*)(bB + k0);
                float4 w1 = *(const float4*)(bB + k0 + 4);
                br_[0]=w0.x; br_[1]=w0.y; br_[2]=w0.z; br_[3]=w0.w;
                br_[4]=w1.x; br_[5]=w1.y; br_[6]=w1.z; br_[7]=w1.w;
            } else {
#pragma unroll
                for (int e = 0; e < 8; ++e)
                    br_[e] = (kb0 + e < K) ? bB[k0 + e] : 0.0f;
            }
            const int kb1 = kb0 + 16;
            if (kb1 + 8 <= K) {
                float4 w0 = *(const float4*)(bB + k0 + 16);
                float4 w1 = *(const float4*)(bB + k0 + 20);
                br_[8]=w0.x;  br_[9]=w0.y;  br_[10]=w0.z; br_[11]=w0.w;
                br_[12]=w1.x; br_[13]=w1.y; br_[14]=w1.z; br_[15]=w1.w;
            } else {
#pragma unroll
                for (int e = 0; e < 8; ++e)
                    br_[8 + e] = (kb1 + e < K) ? bB[k0 + 16 + e] : 0.0f;
            }
        }
    };

    auto write_tile = [&](int buf) {
        uint4 hi, lo;
        split8(ar_, hi, lo);
        *(uint4*)&As_hi[buf][wOffA] = hi;
        *(uint4*)&As_lo[buf][wOffA] = lo;
        split8(br_, hi, lo);
        *(uint4*)&Bs_hi[buf][wOffB0] = hi;
        *(uint4*)&Bs_lo[buf][wOffB0] = lo;
        split8(br_ + 8, hi, lo);
        *(uint4*)&Bs_hi[buf][wOffB1] = hi;
        *(uint4*)&Bs_lo[buf][wOffB1] = lo;
    };

    f32x16 accA, accB;
#pragma unroll
    for (int i = 0; i < 16; ++i) { accA[i] = 0.0f; accB[i] = 0.0f; }

    const int nsteps = (K + 31) >> 5;
    load_regs(0);
    write_tile(0);
    if (nsteps > 1) load_regs(1);
    __syncthreads();

    for (int s = 0; s < nsteps; ++s) {
        const int cur = s & 1;

        bf16x8 a0h = *(const bf16x8*)&As_hi[cur][aOff0];
        bf16x8 a0l = *(const bf16x8*)&As_lo[cur][aOff0];
        bf16x8 a1h = *(const bf16x8*)&As_hi[cur][aOff1];
        bf16x8 a1l = *(const bf16x8*)&As_lo[cur][aOff1];
        bf16x8 b0h = *(const bf16x8*)&Bs_hi[cur][bOff0];
        bf16x8 b0l = *(const bf16x8*)&Bs_lo[cur][bOff0];
        bf16x8 b1h = *(const bf16x8*)&Bs_hi[cur][bOff1];
        bf16x8 b1l = *(const bf16x8*)&Bs_lo[cur][bOff1];

        if (s + 1 < nsteps) write_tile(cur ^ 1);
        if (s + 2 < nsteps) load_regs(s + 2);

        __builtin_amdgcn_s_setprio(1);
        accA = __builtin_amdgcn_mfma_f32_32x32x16_bf16(a0h, b0h, accA, 0,0,0);
        accB = __builtin_amdgcn_mfma_f32_32x32x16_bf16(a1h, b1h, accB, 0,0,0);
        accA = __builtin_amdgcn_mfma_f32_32x32x16_bf16(a0h, b0l, accA, 0,0,0);
        accB = __builtin_amdgcn_mfma_f32_32x32x16_bf16(a1h, b1l, accB, 0,0,0);
        accA = __builtin_amdgcn_mfma_f32_32x32x16_bf16(a0l, b0h, accA, 0,0,0);
        accB = __builtin_amdgcn_mfma_f32_32x32x16_bf16(a1l, b1h, accB, 0,0,0);
        __builtin_amdgcn_s_setprio(0);
        __syncthreads();
    }

    f32x16 acc;
#pragma unroll
    for (int i = 0; i < 16; ++i) acc[i] = accA[i] + accB[i];

    const int col = lane & 31;
    const int rbase = 4 * kh;
#pragma unroll
    for (int r = 0; r < 16; ++r) {
        const int row = (r & 3) + 8 * (r >> 2) + rbase;
        const int gm = m0 + row;
        const int gn = n0 + wid * 32 + col;
        if (gn < Na) {
            float v = acc[r];
            if (ADD_BIAS) v += bias[gn];
            C[(size_t)gm * Na + gn] = v;
        }
    }
}

// ---------------------------------------------------------------------------
// Per-batch-row masking pipeline — EXACT round-12 version.
// sB aliases the xbn region: block stages its sB row into LDS before the
// barrier-ordered overwrite -> safe; no restrict on it.
// ---------------------------------------------------------------------------
__global__ __launch_bounds__(256) void rowproc_kernel(
    const float* __restrict__ zA,     // [B,1000]
    const float* sB,                  // [B,6000] (aliases xbn region)
    const float* __restrict__ phi,    // [B,6000]
    const float* __restrict__ psi,    // [B,6000]
    const float* __restrict__ decay,  // [6000]
    float* xbn, float* __restrict__ phin, float* __restrict__ psin,
    float* __restrict__ lam2)         // [B,1000]
{
    const int b = blockIdx.x;
    const int tid = threadIdx.x;
    const int lane = tid & 63;
    const int wid = tid >> 6;

    __shared__ float sig[6000];
    __shared__ float lam[1000];
    __shared__ int   wi[1000];
    __shared__ int   cw[1000];
    __shared__ float redf[4];

    const size_t rowTC = (size_t)b * 6000;
    const size_t rowM  = (size_t)b * 1000;

    float lmin = FLT_MAX_C;
    for (int t = tid; t < 6000; t += 256) {
        float v = sB[rowTC + t] + zA[rowM + t / 6];
        sig[t] = v;
        lmin = fminf(lmin, v);
    }
#pragma unroll
    for (int off = 32; off > 0; off >>= 1)
        lmin = fminf(lmin, __shfl_down(lmin, off));
    if (lane == 0) redf[wid] = lmin;
    __syncthreads();
    if (tid == 0)
        redf[0] = fminf(fminf(redf[0], redf[1]), fminf(redf[2], redf[3]));
    __syncthreads();
    const float minv = redf[0];

    for (int m = tid; m < 1000; m += 256) {
        float best = -FLT_MAX_C;
        int bj = 0;
#pragma unroll
        for (int j = 0; j < 6; ++j) {
            const int t = m * 6 + j;
            const float p = (1.0f - phi[rowTC + t]) * (sig[t] - minv);
            if (p > best) { best = p; bj = j; }
        }
        lam[m] = best;
        wi[m] = bj;
        cw[m] = 0;
    }
    __syncthreads();

    if (wid == 0) {
        float lv[16];
        int wmask = 0;
#pragma unroll
        for (int j = 0; j < 16; ++j) {
            const int m = lane + (j << 6);
            lv[j] = (m < 1000) ? lam[m] : -FLT_MAX_C;
        }
        for (int it = 0; it < 50; ++it) {
            float bv = -FLT_MAX_C;
            int bi = 0x7fffffff;
#pragma unroll
            for (int j = 0; j < 16; ++j) {
                const int m = lane + (j << 6);
                const float v = lv[j];
                if (v > bv || (v == bv && m < bi)) { bv = v; bi = m; }
            }
#pragma unroll
            for (int off = 32; off > 0; off >>= 1) {
                const float ov = __shfl_xor(bv, off);
                const int oi  = __shfl_xor(bi, off);
                if (ov > bv || (ov == bv && oi < bi)) { bv = ov; bi = oi; }
            }
            if ((bi & 63) == lane) {
                const int jj = bi >> 6;
#pragma unroll
                for (int j = 0; j < 16; ++j)       // static indexing
                    if (j == jj) { lv[j] = -FLT_MAX_C; wmask |= (1 << j); }
            }
        }
#pragma unroll
        for (int j = 0; j < 16; ++j)
            if ((wmask >> j) & 1) cw[lane + (j << 6)] = 1;
    }
    __syncthreads();

    for (int m = tid; m < 1000; m += 256) {
        const int won = cw[m];
        const int bj = wi[m];
        float cmax = -FLT_MAX_C;
        const size_t base = rowTC + (size_t)m * 6;
#pragma unroll
        for (int j = 0; j < 6; ++j) {
            const int t = m * 6 + j;
            const float y = (won && j == bj) ? tanhf(sig[t]) : 0.0f;
            const float pv = fmaxf(psi[base + j] * decay[t], y);
            const float fv = fmaxf(phi[base + j] * 0.5f, y);
            psin[base + j] = pv;
            xbn[base + j]  = pv;
            phin[base + j] = fv;
            cmax = fmaxf(cmax, pv);
        }
        lam2[rowM + m] = cmax;
    }
}

// ---------------------------------------------------------------------------
extern "C" void kernel_launch(void* const* d_in, const int* in_sizes, int n_in,
                              void* d_out, int out_size, void* d_ws, size_t ws_size,
                              hipStream_t stream)
{
    const float* x_a   = (const float*)d_in[0];  // [512,2048]
    const float* x_b   = (const float*)d_in[1];  // [512,6000]
    const float* phi   = (const float*)d_in[2];  // [512,6000]
    const float* psi   = (const float*)d_in[3];  // [512,6000]
    const float* W_a   = (const float*)d_in[4];  // [1000,2048]
    const float* W_b   = (const float*)d_in[5];  // [6000,6000]
    const float* W_d   = (const float*)d_in[6];  // [2048,1000]
    const float* b_d   = (const float*)d_in[7];  // [2048]
    const float* decay = (const float*)d_in[8];  // [6000]

    float* out  = (float*)d_out;                       // [512,2048]
    float* xbn  = out + (size_t)512 * 2048;            // [512,6000]
    float* phin = xbn + (size_t)512 * 6000;            // [512,6000]
    float* psin = phin + (size_t)512 * 6000;           // [512,6000]

    float* lam2 = (float*)d_ws;          // [512,1000] (2 MB)

    // Staging (r4/9/12 proven): z_a in out region (consumed by rowproc before
    // decode GEMM overwrites out); s_b in xbn region (rowproc stages row into
    // LDS before overwriting). A operands from ORIGINAL inputs (r13 lesson).
    float* z_a = out;
    float* s_b = xbn;

    // z_a = x_a @ W_a^T   [512,1000], K=2048; 32x64 tile -> 16 bx * 16 by = 256
    gemm_mfma_split32<false><<<dim3(16 * 16), dim3(128), 0, stream>>>(
        x_a, W_a, nullptr, z_a, 512, 1000, 2048);
    // s_b = x_b @ W_b^T   [512,6000], K=6000; BK=64 64x64 -> 94 bx * 8 by = 752
    gemm_mfma_split64<false><<<dim3(94 * 8), dim3(256), 0, stream>>>(
        x_b, W_b, nullptr, s_b, 512, 6000, 6000);
    // masking pipeline
    rowproc_kernel<<<512, dim3(256), 0, stream>>>(z_a, s_b, phi, psi, decay,
                                                  xbn, phin, psin, lam2);
    // out = lam2 @ W_d^T + b_d   [512,2048], K=1000; 32x64 -> 32 bx * 16 by = 512
    gemm_mfma_split32<true><<<dim3(32 * 16), dim3(128), 0, stream>>>(
        lam2, W_d, b_d, out, 512, 2048, 1000);
}

// Round 17
// 399.619 us; speedup vs baseline: 1.3107x; 1.3107x over previous
//
#include <hip/hip_runtime.h>
#include <hip/hip_bf16.h>
#include <cstddef>
#include <cstdint>

#define FLT_MAX_C 3.402823466e+38f

typedef __attribute__((ext_vector_type(8))) __bf16 bf16x8;
typedef __attribute__((ext_vector_type(16))) float f32x16;

// Truncation-based fp32 -> bf16(hi) + bf16(lo) split (bit-exact, r4/9/12).
__device__ __forceinline__ void split8(const float* v, uint4& hi, uint4& lo) {
    uint32_t hu[8], lu[8];
#pragma unroll
    for (int e = 0; e < 8; ++e) {
        union { float f; uint32_t u; } a, t, d;
        a.f = v[e];
        t.u = a.u & 0xffff0000u;
        d.f = a.f - t.f;
        hu[e] = t.u;
        lu[e] = d.u;
    }
    hi.x = __builtin_amdgcn_perm(hu[1], hu[0], 0x07060302u);
    hi.y = __builtin_amdgcn_perm(hu[3], hu[2], 0x07060302u);
    hi.z = __builtin_amdgcn_perm(hu[5], hu[4], 0x07060302u);
    hi.w = __builtin_amdgcn_perm(hu[7], hu[6], 0x07060302u);
    lo.x = __builtin_amdgcn_perm(lu[1], lu[0], 0x07060302u);
    lo.y = __builtin_amdgcn_perm(lu[3], lu[2], 0x07060302u);
    lo.z = __builtin_amdgcn_perm(lu[5], lu[4], 0x07060302u);
    lo.w = __builtin_amdgcn_perm(lu[7], lu[6], 0x07060302u);
}

// LDS-only barrier (r12, proven): drain ds ops so LDS writes are visible,
// leave GLOBAL loads (vmcnt) in flight across the barrier.
__device__ __forceinline__ void lds_barrier() {
    asm volatile("s_waitcnt lgkmcnt(0)" ::: "memory");
    __builtin_amdgcn_s_barrier();
}

struct LdsBufs {
    alignas(16) unsigned short As_hi[2][2048];
    alignas(16) unsigned short As_lo[2][2048];
    alignas(16) unsigned short Bs_hi[2][2048];
    alignas(16) unsigned short Bs_lo[2][2048];
};

// ---------------------------------------------------------------------------
// 64x64 split-bf16 3-pass MFMA GEMM body — EXACT round-12 kernel (proven
// 300 us s_b, stable across 4 rounds), parameterized by (wgid, nwg) so two
// independent GEMMs can share one dispatch. Arithmetic bit-identical to
// r4/9/12: BK=32 ascending, chains accA (k mod 32 in 0-15) / accB (16-31),
// 6-MFMA order hh,hh,hl,hl,lh,lh, accA+accB at end. Counted-wait barrier +
// double staging regsets. Requires Ma % 64 == 0, even nsteps.
// ---------------------------------------------------------------------------
__device__ __forceinline__ void gemm64_body(
    const float* __restrict__ A, const float* __restrict__ Bm,
    float* __restrict__ C, int Ma, int Na, int K,
    int wgid, int nwg, LdsBufs& L)
{
    const int nby = Ma >> 6;
    // bijective XCD remap (m204) — identical arithmetic to r12's dispatch
    const int qq = nwg >> 3, rr = nwg & 7;
    const int xcd = wgid & 7, lin = wgid >> 3;
    const int wg = ((xcd < rr) ? xcd * (qq + 1) : rr * (qq + 1) + (xcd - rr) * qq) + lin;
    const int by = wg % nby;
    const int bx = wg / nby;

    const int m0 = by * 64;
    const int n0 = bx * 64;

    const int tid  = threadIdx.x;
    const int lane = tid & 63;
    const int wid  = tid >> 6;
    const int wm   = wid >> 1;
    const int wn   = wid & 1;

    const int ra = tid & 63, sa = tid >> 6;

    const float* aB = A + (size_t)(m0 + ra) * K + sa * 8;
    const int gnb = n0 + ra;
    const float* bB = (gnb < Na) ? (Bm + (size_t)gnb * K + sa * 8) : nullptr;

    const int wOff = (sa * 64 + ra) * 8;

    const int lr = lane & 31, kh = lane >> 5;
    const int arow = wm * 32 + lr;
    const int brow = wn * 32 + lr;
    const int aOff0 = ((kh)     * 64 + arow) * 8;
    const int aOff1 = ((2 + kh) * 64 + arow) * 8;
    const int bOff0 = ((kh)     * 64 + brow) * 8;
    const int bOff1 = ((2 + kh) * 64 + brow) * 8;

    float ar0[8], br0[8], ar1[8], br1[8];
#pragma unroll
    for (int e = 0; e < 8; ++e) { br0[e] = 0.0f; br1[e] = 0.0f; }

    auto load_regs = [&](float* arr, float* brr, int s) {
        const int k0 = s << 5;
        const int ka = k0 + sa * 8;
        if (ka + 8 <= K) {
            float4 v0 = *(const float4*)(aB + k0);
            float4 v1 = *(const float4*)(aB + k0 + 4);
            arr[0]=v0.x; arr[1]=v0.y; arr[2]=v0.z; arr[3]=v0.w;
            arr[4]=v1.x; arr[5]=v1.y; arr[6]=v1.z; arr[7]=v1.w;
            if (bB) {
                float4 w0 = *(const float4*)(bB + k0);
                float4 w1 = *(const float4*)(bB + k0 + 4);
                brr[0]=w0.x; brr[1]=w0.y; brr[2]=w0.z; brr[3]=w0.w;
                brr[4]=w1.x; brr[5]=w1.y; brr[6]=w1.z; brr[7]=w1.w;
            }
        } else {
#pragma unroll
            for (int e = 0; e < 8; ++e)
                arr[e] = (ka + e < K) ? aB[k0 + e] : 0.0f;
            if (bB) {
#pragma unroll
                for (int e = 0; e < 8; ++e)
                    brr[e] = (ka + e < K) ? bB[k0 + e] : 0.0f;
            }
        }
    };

    auto write_tile = [&](int buf, const float* arr, const float* brr) {
        uint4 hi, lo;
        split8(arr, hi, lo);
        *(uint4*)&L.As_hi[buf][wOff] = hi;
        *(uint4*)&L.As_lo[buf][wOff] = lo;
        split8(brr, hi, lo);
        *(uint4*)&L.Bs_hi[buf][wOff] = hi;
        *(uint4*)&L.Bs_lo[buf][wOff] = lo;
    };

    f32x16 accA, accB;
#pragma unroll
    for (int i = 0; i < 16; ++i) { accA[i] = 0.0f; accB[i] = 0.0f; }

    auto step_body = [&](int bufR, int bufW, const float* arr, const float* brr,
                         float* arrN, float* brrN, int s) {
        bf16x8 a0h = *(const bf16x8*)&L.As_hi[bufR][aOff0];
        bf16x8 a0l = *(const bf16x8*)&L.As_lo[bufR][aOff0];
        bf16x8 a1h = *(const bf16x8*)&L.As_hi[bufR][aOff1];
        bf16x8 a1l = *(const bf16x8*)&L.As_lo[bufR][aOff1];
        bf16x8 b0h = *(const bf16x8*)&L.Bs_hi[bufR][bOff0];
        bf16x8 b0l = *(const bf16x8*)&L.Bs_lo[bufR][bOff0];
        bf16x8 b1h = *(const bf16x8*)&L.Bs_hi[bufR][bOff1];
        bf16x8 b1l = *(const bf16x8*)&L.Bs_lo[bufR][bOff1];

        const int nst = (K + 31) >> 5;
        if (s + 1 < nst) write_tile(bufW, arr, brr);
        if (s + 3 < nst) load_regs(arrN, brrN, s + 3);

        __builtin_amdgcn_s_setprio(1);
        accA = __builtin_amdgcn_mfma_f32_32x32x16_bf16(a0h, b0h, accA, 0,0,0);
        accB = __builtin_amdgcn_mfma_f32_32x32x16_bf16(a1h, b1h, accB, 0,0,0);
        accA = __builtin_amdgcn_mfma_f32_32x32x16_bf16(a0h, b0l, accA, 0,0,0);
        accB = __builtin_amdgcn_mfma_f32_32x32x16_bf16(a1h, b1l, accB, 0,0,0);
        accA = __builtin_amdgcn_mfma_f32_32x32x16_bf16(a0l, b0h, accA, 0,0,0);
        accB = __builtin_amdgcn_mfma_f32_32x32x16_bf16(a1l, b1h, accB, 0,0,0);
        __builtin_amdgcn_s_setprio(0);

        lds_barrier();
    };

    const int nsteps = (K + 31) >> 5;

    load_regs(ar0, br0, 0);
    write_tile(0, ar0, br0);
    if (nsteps > 1) load_regs(ar0, br0, 1);
    if (nsteps > 2) load_regs(ar1, br1, 2);
    __syncthreads();

    for (int s = 0; s < nsteps; s += 2) {
        step_body(0, 1, ar0, br0, ar0, br0, s);
        if (s + 1 < nsteps)
            step_body(1, 0, ar1, br1, ar1, br1, s + 1);
    }

    f32x16 acc;
#pragma unroll
    for (int i = 0; i < 16; ++i) acc[i] = accA[i] + accB[i];

    const int col = lane & 31;
    const int rbase = 4 * kh;
#pragma unroll
    for (int r = 0; r < 16; ++r) {
        const int row = (r & 3) + 8 * (r >> 2) + rbase;
        const int gm = m0 + wm * 32 + row;
        const int gn = n0 + wn * 32 + col;
        if (gn < Na)
            C[(size_t)gm * Na + gn] = acc[r];
    }
}

// ---------------------------------------------------------------------------
// Fused dispatch: blocks [0,752) run the s_b GEMM with the EXACT r12
// block->tile mapping (nwg=752); blocks [752,880) run the z_a GEMM (nwg=128,
// 64x64 r12 body — z_a per-output accumulation proven decomposition-
// invariant in r10). The two GEMMs are data-independent; fusing removes
// z_a's serial ~20 us + one launch gap.
// ---------------------------------------------------------------------------
__global__ __launch_bounds__(256) void fused_gemm_kernel(
    const float* __restrict__ x_b, const float* __restrict__ W_b,
    float* __restrict__ s_b,
    const float* __restrict__ x_a, const float* __restrict__ W_a,
    float* __restrict__ z_a)
{
    __shared__ LdsBufs L;
    if (blockIdx.x < 752) {
        gemm64_body(x_b, W_b, s_b, 512, 6000, 6000, blockIdx.x, 752, L);
    } else {
        gemm64_body(x_a, W_a, z_a, 512, 1000, 2048, blockIdx.x - 752, 128, L);
    }
}

// ---------------------------------------------------------------------------
// 32x64 / 2-wave GEMM — EXACT r10/r15 kernel (passed; per-output arithmetic
// bit-identical to the 64x64 version). Used for the decode GEMM.
// Requires Ma % 32 == 0.
// ---------------------------------------------------------------------------
template<bool ADD_BIAS>
__global__ __launch_bounds__(128) void gemm_mfma_split32(
    const float* __restrict__ A, const float* __restrict__ Bm,
    const float* __restrict__ bias, float* __restrict__ C,
    int Ma, int Na, int K)
{
    __shared__ alignas(16) unsigned short As_hi[2][1024];
    __shared__ alignas(16) unsigned short As_lo[2][1024];
    __shared__ alignas(16) unsigned short Bs_hi[2][2048];
    __shared__ alignas(16) unsigned short Bs_lo[2][2048];

    const int nby = Ma >> 5;
    const int nwg = gridDim.x;
    const int orig = blockIdx.x;
    const int qq = nwg >> 3, rr = nwg & 7;
    const int xcd = orig & 7, lin = orig >> 3;
    const int wg = ((xcd < rr) ? xcd * (qq + 1) : rr * (qq + 1) + (xcd - rr) * qq) + lin;
    const int by = wg % nby;
    const int bx = wg / nby;

    const int m0 = by * 32;
    const int n0 = bx * 64;

    const int tid  = threadIdx.x;
    const int lane = tid & 63;
    const int wid  = tid >> 6;

    const int ra = tid & 31, sa = tid >> 5;
    const int rb = tid & 63, sb2 = tid >> 6;

    const float* aB = A + (size_t)(m0 + ra) * K + sa * 8;
    const int gnb = n0 + rb;
    const float* bB = (gnb < Na) ? (Bm + (size_t)gnb * K + sb2 * 8) : nullptr;

    const int wOffA  = (sa * 32 + ra) * 8;
    const int wOffB0 = (sb2 * 64 + rb) * 8;
    const int wOffB1 = ((sb2 + 2) * 64 + rb) * 8;

    const int lr = lane & 31, kh = lane >> 5;
    const int brow = wid * 32 + lr;
    const int aOff0 = ((kh)     * 32 + lr) * 8;
    const int aOff1 = ((2 + kh) * 32 + lr) * 8;
    const int bOff0 = ((kh)     * 64 + brow) * 8;
    const int bOff1 = ((2 + kh) * 64 + brow) * 8;

    float ar_[8];
    float br_[16];
#pragma unroll
    for (int e = 0; e < 16; ++e) br_[e] = 0.0f;

    auto load_regs = [&](int s) {
        const int k0 = s << 5;
        const int ka = k0 + sa * 8;
        if (ka + 8 <= K) {
            float4 v0 = *(const float4*)(aB + k0);
            float4 v1 = *(const float4*)(aB + k0 + 4);
            ar_[0]=v0.x; ar_[1]=v0.y; ar_[2]=v0.z; ar_[3]=v0.w;
            ar_[4]=v1.x; ar_[5]=v1.y; ar_[6]=v1.z; ar_[7]=v1.w;
        } else {
#pragma unroll
            for (int e = 0; e < 8; ++e)
                ar_[e] = (ka + e < K) ? aB[k0 + e] : 0.0f;
        }
        if (bB) {
            const int kb0 = k0 + sb2 * 8;
            if (kb0 + 8 <= K) {
                float4 w0 = *(const float4*)(bB + k0);
                float4 w1 = *(const float4*)(bB + k0 + 4);
                br_[0]=w0.x; br_[1]=w0.y; br_[2]=w0.z; br_[3]=w0.w;
                br_[4]=w1.x; br_[5]=w1.y; br_[6]=w1.z; br_[7]=w1.w;
            } else {
#pragma unroll
                for (int e = 0; e < 8; ++e)
                    br_[e] = (kb0 + e < K) ? bB[k0 + e] : 0.0f;
            }
            const int kb1 = kb0 + 16;
            if (kb1 + 8 <= K) {
                float4 w0 = *(const float4*)(bB + k0 + 16);
                float4 w1 = *(const float4*)(bB + k0 + 20);
                br_[8]=w0.x;  br_[9]=w0.y;  br_[10]=w0.z; br_[11]=w0.w;
                br_[12]=w1.x; br_[13]=w1.y; br_[14]=w1.z; br_[15]=w1.w;
            } else {
#pragma unroll
                for (int e = 0; e < 8; ++e)
                    br_[8 + e] = (kb1 + e < K) ? bB[k0 + 16 + e] : 0.0f;
            }
        }
    };

    auto write_tile = [&](int buf) {
        uint4 hi, lo;
        split8(ar_, hi, lo);
        *(uint4*)&As_hi[buf][wOffA] = hi;
        *(uint4*)&As_lo[buf][wOffA] = lo;
        split8(br_, hi, lo);
        *(uint4*)&Bs_hi[buf][wOffB0] = hi;
        *(uint4*)&Bs_lo[buf][wOffB0] = lo;
        split8(br_ + 8, hi, lo);
        *(uint4*)&Bs_hi[buf][wOffB1] = hi;
        *(uint4*)&Bs_lo[buf][wOffB1] = lo;
    };

    f32x16 accA, accB;
#pragma unroll
    for (int i = 0; i < 16; ++i) { accA[i] = 0.0f; accB[i] = 0.0f; }

    const int nsteps = (K + 31) >> 5;
    load_regs(0);
    write_tile(0);
    if (nsteps > 1) load_regs(1);
    __syncthreads();

    for (int s = 0; s < nsteps; ++s) {
        const int cur = s & 1;

        bf16x8 a0h = *(const bf16x8*)&As_hi[cur][aOff0];
        bf16x8 a0l = *(const bf16x8*)&As_lo[cur][aOff0];
        bf16x8 a1h = *(const bf16x8*)&As_hi[cur][aOff1];
        bf16x8 a1l = *(const bf16x8*)&As_lo[cur][aOff1];
        bf16x8 b0h = *(const bf16x8*)&Bs_hi[cur][bOff0];
        bf16x8 b0l = *(const bf16x8*)&Bs_lo[cur][bOff0];
        bf16x8 b1h = *(const bf16x8*)&Bs_hi[cur][bOff1];
        bf16x8 b1l = *(const bf16x8*)&Bs_lo[cur][bOff1];

        if (s + 1 < nsteps) write_tile(cur ^ 1);
        if (s + 2 < nsteps) load_regs(s + 2);

        __builtin_amdgcn_s_setprio(1);
        accA = __builtin_amdgcn_mfma_f32_32x32x16_bf16(a0h, b0h, accA, 0,0,0);
        accB = __builtin_amdgcn_mfma_f32_32x32x16_bf16(a1h, b1h, accB, 0,0,0);
        accA = __builtin_amdgcn_mfma_f32_32x32x16_bf16(a0h, b0l, accA, 0,0,0);
        accB = __builtin_amdgcn_mfma_f32_32x32x16_bf16(a1h, b1l, accB, 0,0,0);
        accA = __builtin_amdgcn_mfma_f32_32x32x16_bf16(a0l, b0h, accA, 0,0,0);
        accB = __builtin_amdgcn_mfma_f32_32x32x16_bf16(a1l, b1h, accB, 0,0,0);
        __builtin_amdgcn_s_setprio(0);
        __syncthreads();
    }

    f32x16 acc;
#pragma unroll
    for (int i = 0; i < 16; ++i) acc[i] = accA[i] + accB[i];

    const int col = lane & 31;
    const int rbase = 4 * kh;
#pragma unroll
    for (int r = 0; r < 16; ++r) {
        const int row = (r & 3) + 8 * (r >> 2) + rbase;
        const int gm = m0 + row;
        const int gn = n0 + wid * 32 + col;
        if (gn < Na) {
            float v = acc[r];
            if (ADD_BIAS) v += bias[gn];
            C[(size_t)gm * Na + gn] = v;
        }
    }
}

// ---------------------------------------------------------------------------
// Per-batch-row masking pipeline — EXACT round-12 version.
// sB aliases the xbn region: block stages its sB row into LDS before the
// barrier-ordered overwrite -> safe; no restrict on it.
// ---------------------------------------------------------------------------
__global__ __launch_bounds__(256) void rowproc_kernel(
    const float* __restrict__ zA,     // [B,1000]
    const float* sB,                  // [B,6000] (aliases xbn region)
    const float* __restrict__ phi,    // [B,6000]
    const float* __restrict__ psi,    // [B,6000]
    const float* __restrict__ decay,  // [6000]
    float* xbn, float* __restrict__ phin, float* __restrict__ psin,
    float* __restrict__ lam2)         // [B,1000]
{
    const int b = blockIdx.x;
    const int tid = threadIdx.x;
    const int lane = tid & 63;
    const int wid = tid >> 6;

    __shared__ float sig[6000];
    __shared__ float lam[1000];
    __shared__ int   wi[1000];
    __shared__ int   cw[1000];
    __shared__ float redf[4];

    const size_t rowTC = (size_t)b * 6000;
    const size_t rowM  = (size_t)b * 1000;

    float lmin = FLT_MAX_C;
    for (int t = tid; t < 6000; t += 256) {
        float v = sB[rowTC + t] + zA[rowM + t / 6];
        sig[t] = v;
        lmin = fminf(lmin, v);
    }
#pragma unroll
    for (int off = 32; off > 0; off >>= 1)
        lmin = fminf(lmin, __shfl_down(lmin, off));
    if (lane == 0) redf[wid] = lmin;
    __syncthreads();
    if (tid == 0)
        redf[0] = fminf(fminf(redf[0], redf[1]), fminf(redf[2], redf[3]));
    __syncthreads();
    const float minv = redf[0];

    for (int m = tid; m < 1000; m += 256) {
        float best = -FLT_MAX_C;
        int bj = 0;
#pragma unroll
        for (int j = 0; j < 6; ++j) {
            const int t = m * 6 + j;
            const float p = (1.0f - phi[rowTC + t]) * (sig[t] - minv);
            if (p > best) { best = p; bj = j; }
        }
        lam[m] = best;
        wi[m] = bj;
        cw[m] = 0;
    }
    __syncthreads();

    if (wid == 0) {
        float lv[16];
        int wmask = 0;
#pragma unroll
        for (int j = 0; j < 16; ++j) {
            const int m = lane + (j << 6);
            lv[j] = (m < 1000) ? lam[m] : -FLT_MAX_C;
        }
        for (int it = 0; it < 50; ++it) {
            float bv = -FLT_MAX_C;
            int bi = 0x7fffffff;
#pragma unroll
            for (int j = 0; j < 16; ++j) {
                const int m = lane + (j << 6);
                const float v = lv[j];
                if (v > bv || (v == bv && m < bi)) { bv = v; bi = m; }
            }
#pragma unroll
            for (int off = 32; off > 0; off >>= 1) {
                const float ov = __shfl_xor(bv, off);
                const int oi  = __shfl_xor(bi, off);
                if (ov > bv || (ov == bv && oi < bi)) { bv = ov; bi = oi; }
            }
            if ((bi & 63) == lane) {
                const int jj = bi >> 6;
#pragma unroll
                for (int j = 0; j < 16; ++j)       // static indexing
                    if (j == jj) { lv[j] = -FLT_MAX_C; wmask |= (1 << j); }
            }
        }
#pragma unroll
        for (int j = 0; j < 16; ++j)
            if ((wmask >> j) & 1) cw[lane + (j << 6)] = 1;
    }
    __syncthreads();

    for (int m = tid; m < 1000; m += 256) {
        const int won = cw[m];
        const int bj = wi[m];
        float cmax = -FLT_MAX_C;
        const size_t base = rowTC + (size_t)m * 6;
#pragma unroll
        for (int j = 0; j < 6; ++j) {
            const int t = m * 6 + j;
            const float y = (won && j == bj) ? tanhf(sig[t]) : 0.0f;
            const float pv = fmaxf(psi[base + j] * decay[t], y);
            const float fv = fmaxf(phi[base + j] * 0.5f, y);
            psin[base + j] = pv;
            xbn[base + j]  = pv;
            phin[base + j] = fv;
            cmax = fmaxf(cmax, pv);
        }
        lam2[rowM + m] = cmax;
    }
}

// ---------------------------------------------------------------------------
extern "C" void kernel_launch(void* const* d_in, const int* in_sizes, int n_in,
                              void* d_out, int out_size, void* d_ws, size_t ws_size,
                              hipStream_t stream)
{
    const float* x_a   = (const float*)d_in[0];  // [512,2048]
    const float* x_b   = (const float*)d_in[1];  // [512,6000]
    const float* phi   = (const float*)d_in[2];  // [512,6000]
    const float* psi   = (const float*)d_in[3];  // [512,6000]
    const float* W_a   = (const float*)d_in[4];  // [1000,2048]
    const float* W_b   = (const float*)d_in[5];  // [6000,6000]
    const float* W_d   = (const float*)d_in[6];  // [2048,1000]
    const float* b_d   = (const float*)d_in[7];  // [2048]
    const float* decay = (const float*)d_in[8];  // [6000]

    float* out  = (float*)d_out;                       // [512,2048]
    float* xbn  = out + (size_t)512 * 2048;            // [512,6000]
    float* phin = xbn + (size_t)512 * 6000;            // [512,6000]
    float* psin = phin + (size_t)512 * 6000;           // [512,6000]

    float* lam2 = (float*)d_ws;          // [512,1000] (2 MB)

    // Staging (r4/9/12 proven): z_a in out region (consumed by rowproc before
    // decode GEMM overwrites out); s_b in xbn region (rowproc stages row into
    // LDS before overwriting). A operands from ORIGINAL inputs (r13 lesson).
    float* z_a = out;
    float* s_b = xbn;

    // Fused s_b + z_a GEMMs: one dispatch, 752 + 128 = 880 blocks.
    fused_gemm_kernel<<<dim3(880), dim3(256), 0, stream>>>(
        x_b, W_b, s_b, x_a, W_a, z_a);
    // masking pipeline
    rowproc_kernel<<<512, dim3(256), 0, stream>>>(z_a, s_b, phi, psi, decay,
                                                  xbn, phin, psin, lam2);
    // out = lam2 @ W_d^T + b_d   [512,2048], K=1000; 32x64 -> 32 bx * 16 by = 512
    gemm_mfma_split32<true><<<dim3(32 * 16), dim3(128), 0, stream>>>(
        lam2, W_d, b_d, out, 512, 2048, 1000);
}